// Round 5
// baseline (98.181 us; speedup 1.0000x reference)
//
#include <hip/hip_runtime.h>
#include <hip/hip_bf16.h>
#include <cstdint>
#include <cstddef>

#define BATCH 16
#define NROWS 4096
#define MROWS 2048
#define DDIM  256
#define NSPLIT 4
#define BM 128               // n-rows per block
#define BN 256               // m-cols per block
#define NCHUNKS 8            // (NROWS/NSPLIT)/BM
#define GKT_TOT 64           // NCHUNKS * (DDIM/32)

typedef __attribute__((ext_vector_type(8))) short short8;
typedef __attribute__((ext_vector_type(4))) float f32x4;

static __device__ __forceinline__ unsigned short f2bf(float f) {
  unsigned int x = __float_as_uint(f);
  x += 0x7fffu + ((x >> 16) & 1u);
  return (unsigned short)(x >> 16);
}

// ---------------- Kernel 1: row L2-normalize + bf16 cast ----------------
__global__ void __launch_bounds__(256) norm_cast(
    const float* __restrict__ x1, const float* __restrict__ x2,
    unsigned short* __restrict__ aout, unsigned short* __restrict__ bout) {
  const int wid  = threadIdx.x >> 6;
  const int lane = threadIdx.x & 63;
  const long long row = (long long)blockIdx.x * 4 + wid;
  const long long R1 = (long long)BATCH * NROWS;
  const long long R2 = (long long)BATCH * MROWS;
  if (row >= R1 + R2) return;
  const float* src; unsigned short* dst;
  if (row < R1) { src = x1 + row * DDIM; dst = aout + row * DDIM; }
  else { long long r2 = row - R1; src = x2 + r2 * DDIM; dst = bout + r2 * DDIM; }
  float4 v = ((const float4*)src)[lane];
  float ss = v.x*v.x + v.y*v.y + v.z*v.z + v.w*v.w;
  #pragma unroll
  for (int o = 32; o >= 1; o >>= 1) ss += __shfl_xor(ss, o, 64);
  float n = sqrtf(ss);
  float sc = 1.0f / fmaxf(n, 1e-12f);
  ushort4 o;
  o.x = f2bf(v.x * sc); o.y = f2bf(v.y * sc);
  o.z = f2bf(v.z * sc); o.w = f2bf(v.w * sc);
  ((ushort4*)dst)[lane] = o;
}

// ---------------- Kernel 2: 2-blocks/CU fused GEMM + column-max ----------------
typedef __attribute__((address_space(1))) const void gas_t;
typedef __attribute__((address_space(3))) void las_t;
#define GLL16(g, l) __builtin_amdgcn_global_load_lds((gas_t*)(g), (las_t*)(l), 16, 0, 0)

// LDS ring: 3 A slots [128 rows][32 k] bf16 = 8 KB each; 3 B slots [256][32] = 16 KB.
// Total 72 KB -> 2 blocks/CU.
#define LDSA(S) (lds + ((S) << 13))
#define LDSB(S) (lds + 24576 + ((S) << 14))

static __device__ __forceinline__ short8 ldsfrag(const char* slot, int row, int pslot) {
  return *(const short8*)(slot + row * 64 + (pslot << 4));
}

__global__ void __launch_bounds__(256, 2) maxsim_gemm2(
    const unsigned short* __restrict__ A,   // [BATCH][NROWS][DDIM]
    const unsigned short* __restrict__ Bm,  // [BATCH][MROWS][DDIM]
    float* __restrict__ partials)           // [NSPLIT][BATCH][MROWS]
{
  __shared__ __align__(16) char lds[73728];

  const int t = threadIdx.x;
  const int lane = t & 63;
  const int w = t >> 6;                                // 4 waves; wave owns cols w*64..+63
  const int lrow = lane & 15;
  const int pslot = (lane >> 4) ^ ((lane >> 1) & 3);   // swizzled 16B sub-slot for frag reads

  // XCD-aware bijective swizzle: 512 blocks, XCD k owns batches {2k,2k+1}.
  const int hw = blockIdx.x;
  const int logical = (hw & 7) * 64 + (hw >> 3);
  const int mt = logical & 7;
  const int grp = logical >> 3;     // 0..63
  const int sp = grp & 3;
  const int bb = grp >> 2;

  const int m0 = mt * BN;
  const int nbase = sp * (NROWS / NSPLIT);

  const unsigned short* Aba = A  + (size_t)bb * NROWS * DDIM;
  const unsigned short* Bba = Bm + ((size_t)bb * MROWS + m0) * DDIM;

  // Per-thread staging bases; source k-slot pre-swizzled: sphys = (lane&3)^((lane>>3)&3).
  const int sph8 = (((lane & 3) ^ ((lane >> 3) & 3)) << 3);
  const int rl = lane >> 2;
  // A slot: 2 loads/thread, chunk c = w*2+i covers rows c*16..+15 (c in 0..7)
  const unsigned short* sA0 = Aba + (size_t)((w*2+0)*16 + rl) * DDIM + sph8;
  const unsigned short* sA1 = Aba + (size_t)((w*2+1)*16 + rl) * DDIM + sph8;
  const int lA0 = (w*2+0)*1024 + lane*16, lA1 = (w*2+1)*1024 + lane*16;
  // B slot: 4 loads/thread, chunk c = w*4+i (c in 0..15)
  const unsigned short* sB0 = Bba + (size_t)((w*4+0)*16 + rl) * DDIM + sph8;
  const unsigned short* sB1 = Bba + (size_t)((w*4+1)*16 + rl) * DDIM + sph8;
  const unsigned short* sB2 = Bba + (size_t)((w*4+2)*16 + rl) * DDIM + sph8;
  const unsigned short* sB3 = Bba + (size_t)((w*4+3)*16 + rl) * DDIM + sph8;
  const int lB0 = (w*4+0)*1024 + lane*16, lB1 = (w*4+1)*1024 + lane*16;
  const int lB2 = (w*4+2)*1024 + lane*16, lB3 = (w*4+3)*1024 + lane*16;

  #define STAGE_A(S, OFF) do { \
    GLL16(sA0 + (OFF), LDSA(S) + lA0); GLL16(sA1 + (OFF), LDSA(S) + lA1); } while (0)
  #define STAGE_B(S, OFF) do { \
    GLL16(sB0 + (OFF), LDSB(S) + lB0); GLL16(sB1 + (OFF), LDSB(S) + lB1); \
    GLL16(sB2 + (OFF), LDSB(S) + lB2); GLL16(sB3 + (OFF), LDSB(S) + lB3); } while (0)

  f32x4 acc[8][4] = {};
  short8 afr[4], bfr[4];
  float cm[4] = {-INFINITY, -INFINITY, -INFINITY, -INFINITY};

  // ---- Prologue: stage gkt=0 and gkt=1 into ring slots 0,1 (12 loads/thread)
  STAGE_A(0, (size_t)nbase * DDIM + 0);
  STAGE_B(0, 0);
  STAGE_A(1, (size_t)nbase * DDIM + 32);
  STAGE_B(1, 32);
  asm volatile("s_waitcnt vmcnt(6)" ::: "memory");   // gkt0 landed; gkt1 in flight
  asm volatile("s_barrier" ::: "memory");

  int cur = 0, s2 = 2;   // read slot = gkt%3; stage slot = (gkt+2)%3
  for (int gkt = 0; gkt < GKT_TOT; ++gkt) {
    const char* sa = LDSA(cur);
    const char* sb = LDSB(cur);
    // stage source for gkt+2 (wraps to junk rows on last 2 iters; never read)
    const int g2 = gkt + 2;
    const int nc2 = (g2 >> 3) & (NCHUNKS - 1);
    const int k2 = (g2 & 7) * 32;
    const size_t offA = (size_t)(nbase + nc2 * BM) * DDIM + k2;

    // ---- Phase 0: read B(4) + A(mi 0-3); stage next-next A; 16 MFMA
    #pragma unroll
    for (int nj = 0; nj < 4; ++nj)
      bfr[nj] = ldsfrag(sb, w*64 + nj*16 + lrow, pslot);
    #pragma unroll
    for (int mi = 0; mi < 4; ++mi)
      afr[mi] = ldsfrag(sa, mi*16 + lrow, pslot);
    STAGE_A(s2, offA);
    asm volatile("s_barrier" ::: "memory");
    __builtin_amdgcn_s_setprio(1);
    #pragma unroll
    for (int mi = 0; mi < 4; ++mi)
      #pragma unroll
      for (int nj = 0; nj < 4; ++nj)
        acc[mi][nj] = __builtin_amdgcn_mfma_f32_16x16x32_bf16(afr[mi], bfr[nj], acc[mi][nj], 0, 0, 0);
    __builtin_amdgcn_s_setprio(0);
    asm volatile("s_barrier" ::: "memory");

    // ---- Phase 1: read A(mi 4-7); stage next-next B; vmcnt; 16 MFMA
    #pragma unroll
    for (int mi = 0; mi < 4; ++mi)
      afr[mi] = ldsfrag(sa, (4+mi)*16 + lrow, pslot);
    STAGE_B(s2, k2);
    asm volatile("s_waitcnt vmcnt(6)" ::: "memory");   // gkt+1's 6 halves landed
    asm volatile("s_barrier" ::: "memory");
    __builtin_amdgcn_s_setprio(1);
    #pragma unroll
    for (int mi = 0; mi < 4; ++mi)
      #pragma unroll
      for (int nj = 0; nj < 4; ++nj)
        acc[4+mi][nj] = __builtin_amdgcn_mfma_f32_16x16x32_bf16(afr[mi], bfr[nj], acc[4+mi][nj], 0, 0, 0);
    __builtin_amdgcn_s_setprio(0);
    asm volatile("s_barrier" ::: "memory");

    // ---- chunk boundary: fold C into running column max, reset acc
    if ((gkt & 7) == 7) {
      #pragma unroll
      for (int nj = 0; nj < 4; ++nj) {
        float v = cm[nj];
        #pragma unroll
        for (int mi = 0; mi < 8; ++mi) {
          v = fmaxf(v, fmaxf(fmaxf(acc[mi][nj][0], acc[mi][nj][1]),
                             fmaxf(acc[mi][nj][2], acc[mi][nj][3])));
          acc[mi][nj] = (f32x4){0.0f, 0.0f, 0.0f, 0.0f};
        }
        cm[nj] = v;
      }
    }
    cur = (cur == 2) ? 0 : cur + 1;
    s2  = (s2 == 2) ? 0 : s2 + 1;
  }
  #undef STAGE_A
  #undef STAGE_B

  // ---- Epilogue: drain DMA; reduce row-max across lane groups; write partials.
  asm volatile("s_waitcnt vmcnt(0)" ::: "memory");
  #pragma unroll
  for (int nj = 0; nj < 4; ++nj) {
    cm[nj] = fmaxf(cm[nj], __shfl_xor(cm[nj], 16, 64));
    cm[nj] = fmaxf(cm[nj], __shfl_xor(cm[nj], 32, 64));
  }
  if (lane < 16) {
    #pragma unroll
    for (int nj = 0; nj < 4; ++nj)
      partials[((size_t)sp * BATCH + bb) * MROWS + m0 + w*64 + nj*16 + lane] = cm[nj];
  }
}

// ---------------- Kernel 3a: per-batch loss ----------------
__global__ void __launch_bounds__(256) batch_loss(
    const float* __restrict__ partials, const float* __restrict__ y,
    float* __restrict__ bloss) {
  __shared__ float red[4];
  const int b = blockIdx.x;
  const int t = threadIdx.x;
  const int lane = t & 63;
  const int w = t >> 6;
  float s = 0.0f;
  for (int m = t; m < MROWS; m += 256) {
    float v = partials[(size_t)b * MROWS + m];
    #pragma unroll
    for (int sp = 1; sp < NSPLIT; ++sp)
      v = fmaxf(v, partials[((size_t)sp * BATCH + b) * MROWS + m]);
    s += v;
  }
  #pragma unroll
  for (int o = 32; o >= 1; o >>= 1) s += __shfl_xor(s, o, 64);
  if (lane == 0) red[w] = s;
  __syncthreads();
  if (t == 0) {
    float sum = red[0] + red[1] + red[2] + red[3];
    float mean = sum / (float)MROWS;
    float yb = y[b];
    float d = mean - yb;
    bloss[b] = d * d;   // Y_SCALE == 1.0
  }
}

// ---------------- Kernel 3b: combine per-batch losses ----------------
__global__ void __launch_bounds__(64) final_sum(
    const float* __restrict__ bloss, float* __restrict__ out) {
  const int t = threadIdx.x;
  float v = (t < BATCH) ? bloss[t] : 0.0f;
  #pragma unroll
  for (int o = 32; o >= 1; o >>= 1) v += __shfl_xor(v, o, 64);
  if (t == 0) out[0] = v;
}

extern "C" void kernel_launch(void* const* d_in, const int* in_sizes, int n_in,
                              void* d_out, int out_size, void* d_ws, size_t ws_size,
                              hipStream_t stream) {
  const float* x1 = (const float*)d_in[0];
  const float* x2 = (const float*)d_in[1];
  const float* y  = (const float*)d_in[2];
  float* out = (float*)d_out;

  unsigned short* aBF = (unsigned short*)d_ws;
  unsigned short* bBF = aBF + (size_t)BATCH * NROWS * DDIM;
  float* partials = (float*)(bBF + (size_t)BATCH * MROWS * DDIM);
  float* bloss = partials + (size_t)NSPLIT * BATCH * MROWS;

  const int totRows = BATCH * (NROWS + MROWS);
  norm_cast<<<(totRows + 3) / 4, 256, 0, stream>>>(x1, x2, aBF, bBF);
  maxsim_gemm2<<<BATCH * 8 * NSPLIT, 256, 0, stream>>>(aBF, bBF, partials);
  batch_loss<<<BATCH, 256, 0, stream>>>(partials, y, bloss);
  final_sum<<<1, 64, 0, stream>>>(bloss, out);
}

// Round 6
// 91.094 us; speedup vs baseline: 1.0778x; 1.0778x over previous
//
#include <hip/hip_runtime.h>
#include <hip/hip_bf16.h>
#include <cstdint>
#include <cstddef>

#define BATCH 16
#define NROWS 4096
#define MROWS 2048
#define DDIM  256
#define NSPLIT 2
#define NCHUNKS 8            // (NROWS/NSPLIT)/256
#define GKT_TOT 64           // NCHUNKS * (DDIM/32)

typedef __attribute__((ext_vector_type(8))) short short8;
typedef __attribute__((ext_vector_type(4))) float f32x4;

static __device__ __forceinline__ unsigned short f2bf(float f) {
  unsigned int x = __float_as_uint(f);
  x += 0x7fffu + ((x >> 16) & 1u);
  return (unsigned short)(x >> 16);
}

// ---------------- Kernel 1: row L2-normalize + bf16 cast ----------------
__global__ void __launch_bounds__(256) norm_cast(
    const float* __restrict__ x1, const float* __restrict__ x2,
    unsigned short* __restrict__ aout, unsigned short* __restrict__ bout) {
  const int wid  = threadIdx.x >> 6;
  const int lane = threadIdx.x & 63;
  const long long row = (long long)blockIdx.x * 4 + wid;
  const long long R1 = (long long)BATCH * NROWS;
  const long long R2 = (long long)BATCH * MROWS;
  if (row >= R1 + R2) return;
  const float* src; unsigned short* dst;
  if (row < R1) { src = x1 + row * DDIM; dst = aout + row * DDIM; }
  else { long long r2 = row - R1; src = x2 + r2 * DDIM; dst = bout + r2 * DDIM; }
  float4 v = ((const float4*)src)[lane];
  float ss = v.x*v.x + v.y*v.y + v.z*v.z + v.w*v.w;
  #pragma unroll
  for (int o = 32; o >= 1; o >>= 1) ss += __shfl_xor(ss, o, 64);
  float n = sqrtf(ss);
  float sc = 1.0f / fmaxf(n, 1e-12f);
  ushort4 o;
  o.x = f2bf(v.x * sc); o.y = f2bf(v.y * sc);
  o.z = f2bf(v.z * sc); o.w = f2bf(v.w * sc);
  ((ushort4*)dst)[lane] = o;
}

// ---------------- Kernel 2: 3-slot-ring fused GEMM + column-max ----------------
// One barrier per K-tile(32): reads, staging, and MFMA share one region so the
// LDS pipe and MFMA pipe overlap via compiler-counted lgkmcnt (no read->MFMA
// barrier). Ring distance 2 makes staging race-free with a single barrier.
typedef __attribute__((address_space(1))) const void gas_t;
typedef __attribute__((address_space(3))) void las_t;
#define GLL16(g, l) __builtin_amdgcn_global_load_lds((gas_t*)(g), (las_t*)(l), 16, 0, 0)

// LDS ring: 3 x (A [256 rows][32 k] 16 KB + B [256][32] 16 KB) = 96 KB.
#define LDSA(S) (lds + ((S) << 14))
#define LDSB(S) (lds + 49152 + ((S) << 14))

static __device__ __forceinline__ short8 ldsfrag(const char* slot, int row, int pslot) {
  return *(const short8*)(slot + row * 64 + (pslot << 4));
}

__global__ void __launch_bounds__(512, 2) maxsim_gemm_ring(
    const unsigned short* __restrict__ A,   // [BATCH][NROWS][DDIM]
    const unsigned short* __restrict__ Bm,  // [BATCH][MROWS][DDIM]
    float* __restrict__ partials)           // [NSPLIT][BATCH][MROWS]
{
  __shared__ __align__(16) char lds[98304];

  const int t = threadIdx.x;
  const int lane = t & 63;
  const int w = t >> 6;
  const int wr = w >> 2;     // n-half (wave owns 128 rows)
  const int wc = w & 3;      // m-quarter (wave owns 64 cols)
  const int lrow = lane & 15;
  const int pslot = (lane >> 4) ^ ((lane >> 1) & 3);  // swizzled 16B slot for frag reads

  // XCD-aware bijective swizzle: 256 blocks, XCD k owns batches {2k,2k+1}.
  const int hw = blockIdx.x;
  const int logical = (hw & 7) * 32 + (hw >> 3);
  const int mt = logical & 7;
  const int grp = logical >> 3;
  const int sp = grp & 1;
  const int bb = grp >> 1;

  const int m0 = mt * 256;
  const int nbase = sp * (NROWS / NSPLIT);

  const unsigned short* Aba = A  + (size_t)bb * NROWS * DDIM;
  const unsigned short* Bba = Bm + ((size_t)bb * MROWS + m0) * DDIM;

  // Staging: slot is [256 rows][32 k]; 512 threads x 2 loads of 16B.
  // chunk c = w*2+i covers rows c*16..+15; source k pre-swizzled.
  const int sph8 = (((lane & 3) ^ ((lane >> 3) & 3)) << 3);
  const int rl = lane >> 2;
  const unsigned short* sA0 = Aba + (size_t)((w*2+0)*16 + rl) * DDIM + sph8;
  const unsigned short* sA1 = Aba + (size_t)((w*2+1)*16 + rl) * DDIM + sph8;
  const unsigned short* sB0 = Bba + (size_t)((w*2+0)*16 + rl) * DDIM + sph8;
  const unsigned short* sB1 = Bba + (size_t)((w*2+1)*16 + rl) * DDIM + sph8;
  const int l0 = (w*2+0)*1024 + lane*16;
  const int l1 = (w*2+1)*1024 + lane*16;

  #define STAGE_A(S, OFF) do { \
    GLL16(sA0 + (OFF), LDSA(S) + l0); GLL16(sA1 + (OFF), LDSA(S) + l1); } while (0)
  #define STAGE_B(S, OFF) do { \
    GLL16(sB0 + (OFF), LDSB(S) + l0); GLL16(sB1 + (OFF), LDSB(S) + l1); } while (0)

  f32x4 acc[8][4] = {};
  short8 afr[4], bfr[4];
  float cm[4] = {-INFINITY, -INFINITY, -INFINITY, -INFINITY};

  // ---- Prologue: stage gkt=0 -> slot0, gkt=1 -> slot1 (8 loads/thread)
  STAGE_A(0, (size_t)nbase * DDIM + 0);
  STAGE_B(0, 0);
  STAGE_A(1, (size_t)nbase * DDIM + 32);
  STAGE_B(1, 32);
  asm volatile("s_waitcnt vmcnt(4)" ::: "memory");   // slot0 landed
  asm volatile("s_barrier" ::: "memory");

  int cur = 0, s2 = 2;   // read slot = gkt%3; stage slot = (gkt+2)%3
  for (int gkt = 0; gkt < GKT_TOT; ++gkt) {
    const char* sa = LDSA(cur);
    const char* sb = LDSB(cur);
    // stage source for gkt+2 (wraps to chunk 0 on last 2 iters; never read)
    const int g2 = gkt + 2;
    const int nc2 = (g2 >> 3) & (NCHUNKS - 1);
    const int k2 = (g2 & 7) * 32;
    const size_t offA = (size_t)(nbase + nc2 * 256) * DDIM + k2;

    // reads (B + first A half), stage, then MFMA — no barrier in between:
    // read->MFMA is a register dep (compiler lgkmcnt); LDS pipe keeps streaming.
    #pragma unroll
    for (int nj = 0; nj < 4; ++nj)
      bfr[nj] = ldsfrag(sb, wc*64 + nj*16 + lrow, pslot);
    #pragma unroll
    for (int mi = 0; mi < 4; ++mi)
      afr[mi] = ldsfrag(sa, wr*128 + mi*16 + lrow, pslot);
    STAGE_A(s2, offA);
    STAGE_B(s2, k2);
    #pragma unroll
    for (int mi = 0; mi < 4; ++mi)
      #pragma unroll
      for (int nj = 0; nj < 4; ++nj)
        acc[mi][nj] = __builtin_amdgcn_mfma_f32_16x16x32_bf16(afr[mi], bfr[nj], acc[mi][nj], 0, 0, 0);
    // second A half overlaps first MFMA cluster
    #pragma unroll
    for (int mi = 0; mi < 4; ++mi)
      afr[mi] = ldsfrag(sa, wr*128 + (4+mi)*16 + lrow, pslot);
    #pragma unroll
    for (int mi = 0; mi < 4; ++mi)
      #pragma unroll
      for (int nj = 0; nj < 4; ++nj)
        acc[4+mi][nj] = __builtin_amdgcn_mfma_f32_16x16x32_bf16(afr[mi], bfr[nj], acc[4+mi][nj], 0, 0, 0);

    // chunk boundary: fold C into running column max, reset acc
    if ((gkt & 7) == 7) {
      #pragma unroll
      for (int nj = 0; nj < 4; ++nj) {
        float v = cm[nj];
        #pragma unroll
        for (int mi = 0; mi < 8; ++mi) {
          v = fmaxf(v, fmaxf(fmaxf(acc[mi][nj][0], acc[mi][nj][1]),
                             fmaxf(acc[mi][nj][2], acc[mi][nj][3])));
          acc[mi][nj] = (f32x4){0.0f, 0.0f, 0.0f, 0.0f};
        }
        cm[nj] = v;
      }
    }

    // single sync point per K-tile: gkt+1's stage (issued last iter) landed.
    asm volatile("s_waitcnt vmcnt(4)" ::: "memory");
    asm volatile("s_barrier" ::: "memory");
    cur = (cur == 2) ? 0 : cur + 1;
    s2  = (s2 == 2) ? 0 : s2 + 1;
  }
  #undef STAGE_A
  #undef STAGE_B

  // ---- Epilogue: drain DMA; cross-wave max via LDS; write partials
  asm volatile("s_waitcnt vmcnt(0)" ::: "memory");
  asm volatile("s_barrier" ::: "memory");
  float* cmax = (float*)lds;   // [2][256]
  #pragma unroll
  for (int nj = 0; nj < 4; ++nj) {
    cm[nj] = fmaxf(cm[nj], __shfl_xor(cm[nj], 16, 64));
    cm[nj] = fmaxf(cm[nj], __shfl_xor(cm[nj], 32, 64));
  }
  if (lane < 16) {
    #pragma unroll
    for (int nj = 0; nj < 4; ++nj)
      cmax[wr * 256 + wc * 64 + nj * 16 + lane] = cm[nj];
  }
  __syncthreads();
  if (t < 256) {
    float v = fmaxf(cmax[t], cmax[256 + t]);
    partials[((size_t)sp * BATCH + bb) * MROWS + m0 + t] = v;
  }
}

// ---------------- Kernel 3a: per-batch loss ----------------
__global__ void __launch_bounds__(256) batch_loss(
    const float* __restrict__ partials, const float* __restrict__ y,
    float* __restrict__ bloss) {
  __shared__ float red[4];
  const int b = blockIdx.x;
  const int t = threadIdx.x;
  const int lane = t & 63;
  const int w = t >> 6;
  float s = 0.0f;
  for (int m = t; m < MROWS; m += 256) {
    float v = partials[(size_t)b * MROWS + m];
    #pragma unroll
    for (int sp = 1; sp < NSPLIT; ++sp)
      v = fmaxf(v, partials[((size_t)sp * BATCH + b) * MROWS + m]);
    s += v;
  }
  #pragma unroll
  for (int o = 32; o >= 1; o >>= 1) s += __shfl_xor(s, o, 64);
  if (lane == 0) red[w] = s;
  __syncthreads();
  if (t == 0) {
    float sum = red[0] + red[1] + red[2] + red[3];
    float mean = sum / (float)MROWS;
    float yb = y[b];
    float d = mean - yb;
    bloss[b] = d * d;   // Y_SCALE == 1.0
  }
}

// ---------------- Kernel 3b: combine per-batch losses ----------------
__global__ void __launch_bounds__(64) final_sum(
    const float* __restrict__ bloss, float* __restrict__ out) {
  const int t = threadIdx.x;
  float v = (t < BATCH) ? bloss[t] : 0.0f;
  #pragma unroll
  for (int o = 32; o >= 1; o >>= 1) v += __shfl_xor(v, o, 64);
  if (t == 0) out[0] = v;
}

extern "C" void kernel_launch(void* const* d_in, const int* in_sizes, int n_in,
                              void* d_out, int out_size, void* d_ws, size_t ws_size,
                              hipStream_t stream) {
  const float* x1 = (const float*)d_in[0];
  const float* x2 = (const float*)d_in[1];
  const float* y  = (const float*)d_in[2];
  float* out = (float*)d_out;

  unsigned short* aBF = (unsigned short*)d_ws;
  unsigned short* bBF = aBF + (size_t)BATCH * NROWS * DDIM;
  float* partials = (float*)(bBF + (size_t)BATCH * MROWS * DDIM);
  float* bloss = partials + (size_t)NSPLIT * BATCH * MROWS;

  const int totRows = BATCH * (NROWS + MROWS);
  norm_cast<<<(totRows + 3) / 4, 256, 0, stream>>>(x1, x2, aBF, bBF);
  maxsim_gemm_ring<<<BATCH * 8 * NSPLIT, 512, 0, stream>>>(aBF, bBF, partials);
  batch_loss<<<BATCH, 256, 0, stream>>>(partials, y, bloss);
  final_sum<<<1, 64, 0, stream>>>(bloss, out);
}